// Round 3
// baseline (195.166 us; speedup 1.0000x reference)
//
#include <hip/hip_runtime.h>
#include <hip/hip_bf16.h>
#include <math.h>

#define NA 2048   // agents (2^11)
#define TT 20     // timesteps
#define KK 32     // neighbors
#define CC 32     // in channels
#define OO 64     // out channels / hidden
#define GG 256    // 4*OO gates

#define NGRP (NA / 16)        // 128 agent-groups (= lstm blocks)
#define NGATH (NA * TT / 16)  // 2560 gather blocks / row-groups
#define FLG_STRIDE 32         // 128B per flag line (1 writer, 1 reader)

typedef __attribute__((ext_vector_type(8))) short short8;
typedef __attribute__((ext_vector_type(4))) float float4v;

__device__ __forceinline__ float fast_rcp(float x) {
    return __builtin_amdgcn_rcpf(x);
}
__device__ __forceinline__ float sigm(float x) {
    return fast_rcp(1.f + __expf(-x));
}
__device__ __forceinline__ float tanh_fast(float x) {
    return 1.f - 2.f * fast_rcp(1.f + __expf(2.f * x));
}
// bf16 RNE on raw bits (ties-to-even; NaN not expected here).
__device__ __forceinline__ unsigned cvt_rne(float f) {
    unsigned u = __float_as_uint(f);
    return (u + 0x7FFFu + ((u >> 16) & 1u)) >> 16;
}
__device__ __forceinline__ unsigned pack2(float a, float b) {
    return cvt_rne(a) | (cvt_rne(b) << 16);
}
__device__ __forceinline__ float bf_lo(unsigned u) {
    return __uint_as_float(u << 16);
}
__device__ __forceinline__ float bf_hi(unsigned u) {
    return __uint_as_float(u & 0xffff0000u);
}

// Wait until producer flag is set. Relaxed polls: no cache invalidation,
// so the gather blocks sharing this XCD keep their L2 P-locality.
__device__ __forceinline__ void wait_flag(const unsigned* f) {
    while (__hip_atomic_load(f, __ATOMIC_RELAXED,
                             __HIP_MEMORY_SCOPE_AGENT) == 0u)
        __builtin_amdgcn_s_sleep(8);
}
// 16B feat fragment via two 8B agent-scope loads (served at the
// coherence point; producer flushed via release-store wbl2).
__device__ __forceinline__ short8 ld_feat16(const void* p) {
    const unsigned long long* q = (const unsigned long long*)p;
    unsigned long long a = __hip_atomic_load(q, __ATOMIC_RELAXED,
                                             __HIP_MEMORY_SCOPE_AGENT);
    unsigned long long b = __hip_atomic_load(q + 1, __ATOMIC_RELAXED,
                                             __HIP_MEMORY_SCOPE_AGENT);
    union { unsigned long long u[2]; short8 s; } v;
    v.u[0] = a; v.u[1] = b;
    return v.s;
}

// P[t][n][o] = sum_c x[n][t][c] * conv_w[o][c], stored bf16 (128B rows).
// Block 0 pre-converts w_ih/w_hh to bf16, precomputes the folded gate
// bias (b_ih + b_hh + conv_b @ w_ih^T), and zeroes the handoff flags
// (re-zeroed every iteration -> safe under workspace re-poison).
__global__ __launch_bounds__(256) void proj_kernel(
    const float* __restrict__ x, const float* __restrict__ conv_w,
    const float* __restrict__ conv_b, const float* __restrict__ w_ih,
    const float* __restrict__ w_hh, const float* __restrict__ b_ih,
    const float* __restrict__ b_hh,
    __hip_bfloat16* __restrict__ P, unsigned short* __restrict__ wihb,
    unsigned short* __restrict__ whhb, float* __restrict__ biasT,
    unsigned* __restrict__ flags)
{
    const int tid = threadIdx.x;
    if (blockIdx.x == 0) {   // prep block
        for (int e = tid; e < 4 * OO * OO; e += 256) {
            wihb[e] = (unsigned short)cvt_rne(w_ih[e]);
            whhb[e] = (unsigned short)cvt_rne(w_hh[e]);
        }
        for (int g = tid; g < NGATH; g += 256)
            flags[(size_t)g * FLG_STRIDE] = 0u;
        float bj = b_ih[tid] + b_hh[tid];
        #pragma unroll
        for (int o = 0; o < OO; o += 4) {
            float4 cb = *(const float4*)(conv_b + o);
            float4 wr = *(const float4*)(w_ih + (size_t)tid * OO + o);
            bj = fmaf(cb.x, wr.x, bj); bj = fmaf(cb.y, wr.y, bj);
            bj = fmaf(cb.z, wr.z, bj); bj = fmaf(cb.w, wr.w, bj);
        }
        biasT[tid] = bj;
        return;
    }
    const int lane = tid & 63;
    const int wv = tid >> 6;
    float w[CC];
    #pragma unroll
    for (int c = 0; c < CC; c += 4) {
        float4 v = *(const float4*)(conv_w + lane * CC + c);
        w[c] = v.x; w[c + 1] = v.y; w[c + 2] = v.z; w[c + 3] = v.w;
    }
    const int rbase = (blockIdx.x - 1) * 16 + wv * 4;
    #pragma unroll
    for (int i = 0; i < 4; ++i) {
        int r = rbase + i;                    // r = n*TT + t (x row order)
        const float* xr = x + (size_t)r * CC;
        float a0 = 0.f, a1 = 0.f;
        #pragma unroll
        for (int c = 0; c < CC; c += 8) {
            float4 v = *(const float4*)(xr + c);
            float4 u = *(const float4*)(xr + c + 4);
            a0 = fmaf(v.x, w[c], a0);     a0 = fmaf(v.y, w[c + 1], a0);
            a0 = fmaf(v.z, w[c + 2], a0); a0 = fmaf(v.w, w[c + 3], a0);
            a1 = fmaf(u.x, w[c + 4], a1); a1 = fmaf(u.y, w[c + 5], a1);
            a1 = fmaf(u.z, w[c + 6], a1); a1 = fmaf(u.w, w[c + 7], a1);
        }
        int n = r / TT;
        int t = r - n * TT;
        ((unsigned short*)P)[(((size_t)t << 11) + n) * OO + lane] =
            (unsigned short)cvt_rne(a0 + a1);
    }
}

// Role-split fused kernel.
// blocks 0..127   : LSTM consumer (agents bid*16..bid*16+15). Dispatched
//                   first -> resident early, overlaps under the gather.
// blocks 128..2687: gather producer (identical math to the proven pure
//                   gather kernel; (bid-128)%8 == bid%8 keeps the XCD
//                   swizzle aligned with hardware assignment).
// Handoff: one flag per (t, agent-group) = per gather block; producer
// release-stores it (flushes its dirty featw lines to the coherence
// point), consumer relax-polls and reads feat via 8B agent-scope loads.
// No deadlock possible: producers wait on nothing.
__global__ __launch_bounds__(256, 4) void gather_lstm_kernel(
    const __hip_bfloat16* __restrict__ P, const int* __restrict__ A,
    unsigned* __restrict__ featw,
    const unsigned short* __restrict__ wihb,
    const unsigned short* __restrict__ whhb,
    const float* __restrict__ biasT, unsigned* __restrict__ flags,
    float* __restrict__ out)
{
    const int tid = threadIdx.x;
    const int lane = tid & 63;
    const int wv = tid >> 6;

    if (blockIdx.x >= NGRP) {
        // ---------------- gather producer ----------------
        __shared__ int A_sh[4][128];        // per-wave: 4 rows x 32 idx
        const int gbid = blockIdx.x - NGRP;
        const int bs = (gbid & 7) * 320 + (gbid >> 3);  // XCD swizzle
        const int r0 = bs << 4;             // 16 rows/block, r = t*NA + n
        const int t = r0 >> 11;             // block never crosses a t-slab
        const unsigned short* Pt =
            (const unsigned short*)P + ((size_t)t << 17);

        const int rw = r0 + wv * 4;         // wave's first row
        ((int2*)A_sh[wv])[lane] = ((const int2*)(A + ((size_t)rw << 5)))[lane];

        const int i_row = lane >> 4;        // 0..3: row within wave
        const int oc8 = lane & 15;          // 8B chunk (4 channels)
        const char* plane = (const char*)Pt + oc8 * 8;
        const int* myA = &A_sh[wv][i_row * 32];

        const int nself = (rw + i_row) & (NA - 1);
        const uint2 su = *(const uint2*)(plane + ((size_t)nself << 7));

        float m0 = -INFINITY, m1 = -INFINITY;
        float m2 = -INFINITY, m3 = -INFINITY;
        #pragma unroll
        for (int bb = 0; bb < 2; ++bb) {
            int idx[16];
            #pragma unroll
            for (int g = 0; g < 16; ++g)    // broadcast ds_read_b32
                idx[g] = myA[bb * 16 + g];
            uint2 uv[16];                   // 32 VGPRs in-flight payload
            #pragma unroll
            for (int g = 0; g < 16; ++g)
                uv[g] = *(const uint2*)(plane + ((size_t)idx[g] << 7));
            #pragma unroll
            for (int g = 0; g < 16; ++g) {
                m0 = fmaxf(m0, bf_lo(uv[g].x)); m1 = fmaxf(m1, bf_hi(uv[g].x));
                m2 = fmaxf(m2, bf_lo(uv[g].y)); m3 = fmaxf(m3, bf_hi(uv[g].y));
            }
        }
        uint2 pk;
        pk.x = pack2(m0 - bf_lo(su.x), m1 - bf_hi(su.x));
        pk.y = pack2(m2 - bf_lo(su.y), m3 - bf_hi(su.y));
        *(uint2*)&featw[((size_t)(rw + i_row) << 5) + oc8 * 2] = pk;

        __syncthreads();                    // all featw stores in L2
        if (tid == 0)
            __hip_atomic_store(flags + (size_t)bs * FLG_STRIDE, 1u,
                               __ATOMIC_RELEASE, __HIP_MEMORY_SCOPE_AGENT);
        return;
    }

    // ---------------- LSTM consumer ----------------
    const int l15 = lane & 15;
    const int q = lane >> 4;
    const int bid = blockIdx.x;           // == agent group a0>>4
    const int a0 = bid * 16;
    const int ch = wv * 16 + l15;         // this lane's channel

    // B-frags: gate g tile needs w rows g*64+ch (bf16, preconverted).
    short8 bfI[4][2], bfH[4][2];
    #pragma unroll
    for (int g = 0; g < 4; ++g) {
        int row = g * 64 + ch;
        #pragma unroll
        for (int ks = 0; ks < 2; ++ks) {
            bfI[g][ks] =
                *(const short8*)(wihb + ((size_t)row << 6) + ks * 32 + q * 8);
            bfH[g][ks] =
                *(const short8*)(whhb + ((size_t)row << 6) + ks * 32 + q * 8);
        }
    }
    float bias_g[4];
    #pragma unroll
    for (int g = 0; g < 4; ++g)
        bias_g[g] = biasT[g * 64 + ch];

    __shared__ __align__(16) unsigned short h_sh[2][16 * 72];  // dbuf

    for (int e = tid; e < 16 * 72 / 2; e += 256)
        ((unsigned*)h_sh[0])[e] = 0u;

    float cst[4] = {0.f, 0.f, 0.f, 0.f};

    const unsigned short* feat = (const unsigned short*)featw;

    // wait for slab 0's producer, preload ff; pre-verify slab 1
    wait_flag(flags + (size_t)(0 * NGRP + bid) * FLG_STRIDE);
    short8 ff[2];
    #pragma unroll
    for (int ks = 0; ks < 2; ++ks)
        ff[ks] = ld_feat16(feat + (((size_t)a0 + l15) << 6) + ks * 32 + q * 8);
    if (TT > 1)
        wait_flag(flags + (size_t)(1 * NGRP + bid) * FLG_STRIDE);

    __syncthreads();  // h_sh[0] ready

    for (int t = 0; t < TT; ++t) {
        // A-frag of h from the current buffer
        short8 ah[2];
        #pragma unroll
        for (int ks = 0; ks < 2; ++ks)
            ah[ks] = *(const short8*)(
                &h_sh[t & 1][l15 * 72 + ks * 32 + q * 8]);

        float4v acc[4] = {{0.f, 0.f, 0.f, 0.f}, {0.f, 0.f, 0.f, 0.f},
                          {0.f, 0.f, 0.f, 0.f}, {0.f, 0.f, 0.f, 0.f}};
        #pragma unroll
        for (int ks = 0; ks < 2; ++ks) {
            #pragma unroll
            for (int g = 0; g < 4; ++g) {
                acc[g] = __builtin_amdgcn_mfma_f32_16x16x32_bf16(
                    ff[ks], bfI[g][ks], acc[g], 0, 0, 0);
                acc[g] = __builtin_amdgcn_mfma_f32_16x16x32_bf16(
                    ah[ks], bfH[g][ks], acc[g], 0, 0, 0);
            }
        }

        // prefetch next step's feat frags (flag verified 1 step ago)
        short8 ffn[2];
        int tn = (t + 1 < TT) ? t + 1 : t;
        #pragma unroll
        for (int ks = 0; ks < 2; ++ks)
            ffn[ks] = ld_feat16(
                feat + ((((size_t)tn << 11) + a0 + l15) << 6) + ks * 32 + q * 8);
        // verify slab t+2 now; ~600cy LLC poll hides under pointwise
        if (t + 2 < TT)
            wait_flag(flags + (size_t)((t + 2) * NGRP + bid) * FLG_STRIDE);

        // pointwise fully in-register: lane holds i/f/g/o for
        // agent q*4+rg at channel ch.
        #pragma unroll
        for (int rg = 0; rg < 4; ++rg) {
            float gi = acc[0][rg] + bias_g[0];
            float gf = acc[1][rg] + bias_g[1];
            float gz = acc[2][rg] + bias_g[2];
            float go = acc[3][rg] + bias_g[3];
            float ig = sigm(gi);
            float fg = sigm(gf);
            float zg = tanh_fast(gz);
            float og = sigm(go);
            cst[rg] = fmaf(fg, cst[rg], ig * zg);
            float hv = og * tanh_fast(cst[rg]);
            int agent = q * 4 + rg;
            h_sh[(t + 1) & 1][agent * 72 + ch] = (unsigned short)cvt_rne(hv);
            out[(((size_t)(a0 + agent) * TT + t) << 6) + ch] = hv;
            if (t == TT - 1) {
                size_t hb = (size_t)NA * TT * OO;
                out[hb + ((size_t)(a0 + agent) << 6) + ch] = hv;
                out[hb + ((size_t)NA << 6) + ((size_t)(a0 + agent) << 6) + ch] =
                    cst[rg];
            }
        }
        __syncthreads();  // h_sh[(t+1)&1] ready for everyone
        ff[0] = ffn[0]; ff[1] = ffn[1];
    }
}

extern "C" void kernel_launch(void* const* d_in, const int* in_sizes, int n_in,
                              void* d_out, int out_size, void* d_ws, size_t ws_size,
                              hipStream_t stream) {
    const float* x      = (const float*)d_in[0];
    const int*   A      = (const int*)  d_in[1];
    const float* conv_w = (const float*)d_in[2];
    const float* conv_b = (const float*)d_in[3];
    const float* w_ih   = (const float*)d_in[4];
    const float* w_hh   = (const float*)d_in[5];
    const float* b_ih   = (const float*)d_in[6];
    const float* b_hh   = (const float*)d_in[7];
    float* out = (float*)d_out;

    char* ws = (char*)d_ws;
    __hip_bfloat16* P  = (__hip_bfloat16*)ws;                    // 5.25 MB
    size_t offF = (size_t)TT * NA * OO * 2;
    unsigned* featw = (unsigned*)(ws + offF);                    // 5.25 MB
    size_t offW = offF + (size_t)TT * NA * OO * 2;
    unsigned short* wihb = (unsigned short*)(ws + offW);         // 32 KB
    unsigned short* whhb = wihb + 4 * OO * OO;                   // 32 KB
    float* biasT = (float*)(whhb + 4 * OO * OO);                 // 1 KB
    unsigned* flags = (unsigned*)(ws + offW + 65536 + 1024);     // 320 KB

    hipLaunchKernelGGL(proj_kernel, dim3(NA * TT / 16 + 1), dim3(256), 0, stream,
                       x, conv_w, conv_b, w_ih, w_hh, b_ih, b_hh,
                       P, wihb, whhb, biasT, flags);
    hipLaunchKernelGGL(gather_lstm_kernel, dim3(NGRP + NGATH), dim3(256), 0,
                       stream, P, A, featw, wihb, whhb, biasT, flags, out);
}